// Round 3
// baseline (602.172 us; speedup 1.0000x reference)
//
#include <hip/hip_runtime.h>

// SpikeFP64ScaleBy2K: each row of 64 {0,1}-floats is a fp64 bit pattern,
// big-endian (element 0 = fp64 bit 63 = sign). out = x with exponent
// (e_x + int(k)) mod 2048; passthrough when k == +/-0. Integer bit ops
// reproduce the float reference exactly (absmax 0, verified R1/R2).
//
// R3: persistent grid-stride waves + prefetch double-buffer (2 tiles in
// flight per wave). Element-order bit packing (no bit-reversal LUT):
//   - 32-bit masks cover elements 0..31 (all fields live there): 8 shfls.
//   - fields extracted via one v_bfrev_b32 each (MSB-first <-> int).
//   - kzero via a single __ballot + 16-bit group field test.
//   - all-integer epilogue: only elements 1..11 change; bits stored as
//     0x3F800000u / 0u, everything else is a raw passthrough of x's words.

typedef unsigned int u32x4 __attribute__((ext_vector_type(4)));

__global__ __launch_bounds__(256) void spike_fp64_scale_kernel(
    const u32x4* __restrict__ x4,
    const u32x4* __restrict__ k4,
    u32x4* __restrict__ o4,
    int ntiles)   // tile = 4 rows = 64 u32x4 = one wave-iteration
{
    const int nwaves = (int)((gridDim.x * blockDim.x) >> 6);
    const int wid    = (int)((blockIdx.x * blockDim.x + threadIdx.x) >> 6);
    const int lane   = (int)(threadIdx.x & 63);
    const int g      = lane >> 4;      // row within tile (0..3)
    const int j      = lane & 15;      // u32x4 within row (0..15)

    if (wid >= ntiles) return;

    size_t idx        = (size_t)wid * 64 + lane;
    const size_t step = (size_t)nwaves * 64;

    u32x4 xv = x4[idx];
    u32x4 kv = k4[idx];

    int tile = wid;
    for (;;) {
        const int  nxt      = tile + nwaves;
        const bool has_next = nxt < ntiles;
        u32x4 xn, kn;
        if (has_next) {            // prefetch next tile while computing this one
            xn = x4[idx + step];
            kn = k4[idx + step];
        }

        // ---- pack: nibble bit b = element (4j+b) of this row ----
        // 1.0f = 0x3F800000 -> value bit is bit 23 of the word.
        const unsigned nx = ((xv[0] >> 23) & 1u) | ((xv[1] >> 22) & 2u)
                          | ((xv[2] >> 21) & 4u) | ((xv[3] >> 20) & 8u);
        const unsigned nk = ((kv[0] >> 23) & 1u) | ((kv[1] >> 22) & 2u)
                          | ((kv[2] >> 21) & 4u) | ((kv[3] >> 20) & 8u);

        // element-order 32-bit masks (elements 0..31; all needed fields live here)
        const unsigned sh4 = (unsigned)(j & 7) * 4u;
        unsigned uxl = (j < 8) ? (nx << sh4) : 0u;
        unsigned ukl = (j < 8) ? (nk << sh4) : 0u;

        // kzero: any of k's elements 1..63 set? (lane j==0 excludes element 0)
        const unsigned nkm = nk & ((j == 0) ? 0xEu : 0xFu);
        const unsigned long long bal = __ballot(nkm != 0u);
        const bool kany = ((unsigned)((bal >> (g * 16)) & 0xFFFFull)) != 0u;

        // OR-reduce across the 16-lane group (masks 1..8 stay in-group)
        #pragma unroll
        for (int m = 1; m <= 8; m <<= 1) {
            uxl |= (unsigned)__shfl_xor((int)uxl, m, 64);
            ukl |= (unsigned)__shfl_xor((int)ukl, m, 64);
        }

        // ---- fields (element e at bit e; bitreverse -> element e at bit 31-e) ----
        const unsigned bk    = __builtin_bitreverse32(ukl);
        const unsigned ek    = (bk >> 20) & 0x7FFu;            // elements 1..11, MSB-first
        const unsigned val16 = 0x8000u | ((bk >> 5) & 0x7FFFu); // [1, m_k top 15]
        const unsigned shv   = (ek + 1u) & 15u;                 // (e_k-1023) mod 16
        const unsigned kabs  = (val16 >> (15u - shv)) & 0x7FFu; // |k| as integer
        const unsigned kfin  = (ukl & 1u) ? ((0u - kabs) & 0x7FFu) : kabs;
        const unsigned ex    = (__builtin_bitreverse32(uxl) >> 20) & 0x7FFu;
        const unsigned enew  = (ex + kfin) & 0x7FFu;

        // ---- all-integer epilogue: only elements 1..11 change ----
        u32x4 o;
        const int e0 = 4 * j;
        #pragma unroll
        for (int c = 0; c < 4; ++c) {
            const int e = e0 + c;
            const unsigned bit  = (enew >> (((unsigned)(11 - e)) & 31u)) & 1u;
            const bool     repl = kany && (e >= 1) && (e <= 11);
            o[c] = repl ? (bit ? 0x3F800000u : 0u) : xv[c];
        }
        __builtin_nontemporal_store(o, &o4[idx]);

        if (!has_next) break;
        tile = nxt;
        idx += step;
        xv = xn;
        kv = kn;
    }
}

extern "C" void kernel_launch(void* const* d_in, const int* in_sizes, int n_in,
                              void* d_out, int out_size, void* d_ws, size_t ws_size,
                              hipStream_t stream) {
    const u32x4* x4 = (const u32x4*)d_in[0];
    const u32x4* k4 = (const u32x4*)d_in[1];
    u32x4* o4 = (u32x4*)d_out;

    const int nrows  = in_sizes[0] / 64;   // 1048576
    const int ntiles = nrows / 4;          // 262144 (nrows is a multiple of 4)

    // Persistent grid: 2048 blocks x 256 thr = 8192 waves -> 32 tiles/wave,
    // 8 blocks/CU (VGPR use is low; full 32-wave occupancy).
    const int threads = 256;
    int blocks = 2048;
    const int max_blocks = (ntiles * 64 + threads - 1) / threads;
    if (blocks > max_blocks) blocks = max_blocks;

    spike_fp64_scale_kernel<<<blocks, threads, 0, stream>>>(x4, k4, o4, ntiles);
}

// Round 4
// 564.337 us; speedup vs baseline: 1.0670x; 1.0670x over previous
//
#include <hip/hip_runtime.h>

// SpikeFP64ScaleBy2K: each row of 64 {0,1}-floats is a fp64 bit pattern,
// big-endian (element 0 = fp64 bit 63 = sign). out = x with exponent
// (e_x + int(k)) mod 2048; passthrough when k == +/-0. Integer bit ops
// reproduce the float reference exactly (absmax 0, verified R1-R3).
//
// R4: R2's one-shot wave structure (it beat R3's persistent loop) +
// R3's integer pack/epilogue + DPP-based 16-lane OR-reduce (VALU pipe,
// replaces 8 DS-pipe shfl_xor ops; no lgkmcnt dependency chain):
//   xor1 = quad_perm[1,0,3,2] (0xB1), xor2 = quad_perm[2,3,0,1] (0x4E),
//   xor7 = row_half_mirror (0x141), xor15 = row_mirror (0x140).

typedef unsigned int u32x4 __attribute__((ext_vector_type(4)));

#define DPP_OR(v, ctrl) \
    (v | (unsigned)__builtin_amdgcn_update_dpp(0, (int)(v), (ctrl), 0xF, 0xF, true))

__global__ __launch_bounds__(256) void spike_fp64_scale_kernel(
    const u32x4* __restrict__ x4,
    const u32x4* __restrict__ k4,
    u32x4* __restrict__ o4)
{
    const int lane = (int)(threadIdx.x & 63);
    const int g    = lane >> 4;      // row within wave (0..3)
    const int j    = lane & 15;      // u32x4 within row (0..15)

    const size_t idx = (size_t)((blockIdx.x * blockDim.x + threadIdx.x) >> 6) * 64 + lane;
    const u32x4 xv = x4[idx];
    const u32x4 kv = k4[idx];

    // ---- pack: nibble bit b = element (4j+b); 1.0f = 0x3F800000, bit 23 ----
    const unsigned nx = ((xv[0] >> 23) & 1u) | ((xv[1] >> 22) & 2u)
                      | ((xv[2] >> 21) & 4u) | ((xv[3] >> 20) & 8u);
    const unsigned nk = ((kv[0] >> 23) & 1u) | ((kv[1] >> 22) & 2u)
                      | ((kv[2] >> 21) & 4u) | ((kv[3] >> 20) & 8u);

    // element-order 32-bit masks (elements 0..31 hold every needed field)
    const unsigned sh4 = (unsigned)(j & 7) * 4u;
    unsigned uxl = (j < 8) ? (nx << sh4) : 0u;
    unsigned ukl = (j < 8) ? (nk << sh4) : 0u;

    // kzero: any of k's elements 1..63 set? (j==0 excludes element 0 = sign)
    const unsigned nkm = nk & ((j == 0) ? 0xEu : 0xFu);
    const unsigned long long bal = __ballot(nkm != 0u);
    const bool kany = ((unsigned)((bal >> (g * 16)) & 0xFFFFull)) != 0u;

    // ---- 16-lane OR-reduce on the VALU pipe (DPP) ----
    uxl = DPP_OR(uxl, 0xB1);  ukl = DPP_OR(ukl, 0xB1);   // xor 1
    uxl = DPP_OR(uxl, 0x4E);  ukl = DPP_OR(ukl, 0x4E);   // xor 2
    uxl = DPP_OR(uxl, 0x141); ukl = DPP_OR(ukl, 0x141);  // xor 7 (half mirror)
    uxl = DPP_OR(uxl, 0x140); ukl = DPP_OR(ukl, 0x140);  // xor 15 (mirror)

    // ---- fields (element e at bit e; bitreverse -> element e at bit 31-e) ----
    const unsigned bk    = __builtin_bitreverse32(ukl);
    const unsigned ek    = (bk >> 20) & 0x7FFu;             // e_k, MSB-first
    const unsigned val16 = 0x8000u | ((bk >> 5) & 0x7FFFu); // [1, m_k top 15]
    const unsigned shv   = (ek + 1u) & 15u;                 // (e_k-1023) mod 16
    const unsigned kabs  = (val16 >> (15u - shv)) & 0x7FFu; // |k| as integer
    const unsigned kfin  = (ukl & 1u) ? ((0u - kabs) & 0x7FFu) : kabs;
    const unsigned ex    = (__builtin_bitreverse32(uxl) >> 20) & 0x7FFu;
    const unsigned enew  = (ex + kfin) & 0x7FFu;

    // ---- all-integer epilogue: only elements 1..11 change ----
    u32x4 o;
    const int e0 = 4 * j;
    #pragma unroll
    for (int c = 0; c < 4; ++c) {
        const int e = e0 + c;
        const unsigned bit  = (enew >> (((unsigned)(11 - e)) & 31u)) & 1u;
        const bool     repl = kany && (e >= 1) && (e <= 11);
        o[c] = repl ? (bit ? 0x3F800000u : 0u) : xv[c];
    }
    o4[idx] = o;
}

extern "C" void kernel_launch(void* const* d_in, const int* in_sizes, int n_in,
                              void* d_out, int out_size, void* d_ws, size_t ws_size,
                              hipStream_t stream) {
    const u32x4* x4 = (const u32x4*)d_in[0];
    const u32x4* k4 = (const u32x4*)d_in[1];
    u32x4* o4 = (u32x4*)d_out;

    const int nrows = in_sizes[0] / 64;      // 1048576
    const int total_threads = nrows * 16;    // 16 lanes per row
    const int threads = 256;
    const int blocks = total_threads / threads;  // 65536, exact (full waves)

    spike_fp64_scale_kernel<<<blocks, threads, 0, stream>>>(x4, k4, o4);
}